// Round 2
// baseline (339.308 us; speedup 1.0000x reference)
//
#include <hip/hip_runtime.h>
#include <hip/hip_bf16.h>

// Flash-style block attention, MI355X gfx950.
// B=4,H=16,T=4096,d=64,G=128,BLOCK=128 -> 2048 WGs, 256 thr (4 waves).
// Wave owns 32 q-rows. Online softmax over 4 key-chunks of 64 (2 local + 2 global).
// fp32 accuracy via bf16 hi/lo split (3 MFMA per product term).

typedef __attribute__((ext_vector_type(8))) short bf16x8;
typedef __attribute__((ext_vector_type(4))) float f32x4;

#define MFMA(A, B, C) __builtin_amdgcn_mfma_f32_16x16x32_bf16((A), (B), (C), 0, 0, 0)

union BF8 { bf16x8 v; unsigned int w[4]; };

__device__ __forceinline__ unsigned int cvt_pk(float a, float b) {
    __hip_bfloat162 h = __float22bfloat162_rn(float2{a, b});
    union { __hip_bfloat162 h; unsigned int u; } c;
    c.h = h;
    return c.u;
}
__device__ __forceinline__ void split2(float a, float b, unsigned int& hi, unsigned int& lo) {
    unsigned int h = cvt_pk(a, b);
    float ra = a - __uint_as_float(h << 16);
    float rb = b - __uint_as_float(h & 0xFFFF0000u);
    hi = h;
    lo = cvt_pk(ra, rb);
}
__device__ __forceinline__ void split8v(f32x4 a, f32x4 b, bf16x8& hi, bf16x8& lo) {
    BF8 H, L;
    split2(a[0], a[1], H.w[0], L.w[0]);
    split2(a[2], a[3], H.w[1], L.w[1]);
    split2(b[0], b[1], H.w[2], L.w[2]);
    split2(b[2], b[3], H.w[3], L.w[3]);
    hi = H.v; lo = L.v;
}

__global__ __launch_bounds__(256, 3) void block_attn_kernel(
    const float* __restrict__ q, const float* __restrict__ k,
    const float* __restrict__ v, const float* __restrict__ amask,
    const float* __restrict__ gk, const float* __restrict__ gv,
    const float* __restrict__ gmask, float* __restrict__ out) {
    constexpr int Hh = 16, Tt = 4096, Gg = 128;

    // LDS: one 64x64 hi/lo bf16 buffer (stride 72) shared by K then V^T per chunk,
    // plus per-wave P-transpose scratch [16][68] fp32. Total 35840 B -> LDS allows 4 blk/CU.
    __shared__ __align__(16) unsigned char lds[35840];
    unsigned short* kv_hi = (unsigned short*)(lds);         // [64][72]
    unsigned short* kv_lo = (unsigned short*)(lds + 9216);  // [64][72]
    float* p_scr = (float*)(lds + 18432);                   // [4 waves][16][68]

    const int blk = blockIdx.x;
    const int bh  = blockIdx.z * Hh + blockIdx.y;
    const int tid  = threadIdx.x;
    const int lane = tid & 63;
    const int wv   = tid >> 6;
    const int c15  = lane & 15;
    const int quad = lane >> 4;

    const float* qptr = q + ((size_t)bh * Tt + blk * 128) * 64;
    const float* kptr = k + ((size_t)bh * Tt + blk * 128) * 64;
    const float* vptr = v + ((size_t)bh * Tt + blk * 128) * 64;
    const float* gkp  = gk + (size_t)bh * Gg * 64;
    const float* gvp  = gv + (size_t)bh * Gg * 64;
    const float* amp  = amask + (size_t)bh * Tt + blk * 128;
    const float* gmp  = gmask + (size_t)bh * Gg;

    // ---- Q fragments: global -> registers (A-layout: m=c15, k=quad*8+j+32h) ----
    bf16x8 qh[2][2], ql[2][2];
#pragma unroll
    for (int mt = 0; mt < 2; ++mt) {
        int row = wv * 32 + mt * 16 + c15;
#pragma unroll
        for (int h = 0; h < 2; ++h) {
            f32x4 a = *(const f32x4*)(qptr + row * 64 + h * 32 + quad * 8);
            f32x4 b = *(const f32x4*)(qptr + row * 64 + h * 32 + quad * 8 + 4);
            split8v(a, b, qh[mt][h], ql[mt][h]);
        }
    }

    const f32x4 zero4 = {0.f, 0.f, 0.f, 0.f};
    f32x4 ctx[2][4];
    float m_run[2][4], l_run[2][4];
#pragma unroll
    for (int mt = 0; mt < 2; ++mt) {
#pragma unroll
        for (int i = 0; i < 4; ++i) {
            ctx[mt][i] = zero4;
            m_run[mt][i] = -3.4e38f;
            l_run[mt][i] = 0.f;
        }
    }

    float* pw = p_scr + wv * (16 * 68);

#pragma unroll
    for (int c = 0; c < 4; ++c) {
        __syncthreads();  // prior chunk's V^T reads done before K overwrites region

        // ---- stage K chunk (64 keys x 64 d) as hi/lo bf16, stride 72 ----
        {
            const float* ks = (c < 2) ? (kptr + c * 64 * 64) : (gkp + (c - 2) * 64 * 64);
            const int slot = tid & 15, r0 = tid >> 4;
#pragma unroll
            for (int i = 0; i < 4; ++i) {
                int row = r0 + i * 16;
                f32x4 val = *(const f32x4*)(ks + row * 64 + slot * 4);
                unsigned int h0, l0, h1, l1;
                split2(val[0], val[1], h0, l0);
                split2(val[2], val[3], h1, l1);
                int base = row * 72 + slot * 4;
                *reinterpret_cast<uint2*>(kv_hi + base) = make_uint2(h0, h1);
                *reinterpret_cast<uint2*>(kv_lo + base) = make_uint2(l0, l1);
            }
        }
        __syncthreads();

        // ---- S = QK^T for this chunk ----
        f32x4 S[2][4];
#pragma unroll
        for (int mt = 0; mt < 2; ++mt)
#pragma unroll
            for (int nt = 0; nt < 4; ++nt) S[mt][nt] = zero4;

#pragma unroll
        for (int nt = 0; nt < 4; ++nt) {
            int krow = nt * 16 + c15;
            bf16x8 kh0 = *(const bf16x8*)(kv_hi + krow * 72 + quad * 8);
            bf16x8 kh1 = *(const bf16x8*)(kv_hi + krow * 72 + quad * 8 + 32);
            bf16x8 kl0 = *(const bf16x8*)(kv_lo + krow * 72 + quad * 8);
            bf16x8 kl1 = *(const bf16x8*)(kv_lo + krow * 72 + quad * 8 + 32);
#pragma unroll
            for (int mt = 0; mt < 2; ++mt) {
                f32x4 a = S[mt][nt];
                a = MFMA(qh[mt][0], kh0, a);
                a = MFMA(qh[mt][1], kh1, a);
                a = MFMA(ql[mt][0], kh0, a);
                a = MFMA(ql[mt][1], kh1, a);
                a = MFMA(qh[mt][0], kl0, a);
                a = MFMA(qh[mt][1], kl1, a);
                S[mt][nt] = a;
            }
        }

        // ---- online softmax update (registers only) ----
        {
            const float* mbase = (c < 2) ? (amp + c * 64) : (gmp + (c - 2) * 64);
            float mv[4];
#pragma unroll
            for (int nt = 0; nt < 4; ++nt) mv[nt] = mbase[nt * 16 + c15];

#pragma unroll
            for (int mt = 0; mt < 2; ++mt) {
#pragma unroll
                for (int r = 0; r < 4; ++r) {
                    float mx = -3.4e38f;
#pragma unroll
                    for (int nt = 0; nt < 4; ++nt) {
                        float s = S[mt][nt][r] * 0.125f + mv[nt];
                        S[mt][nt][r] = s;
                        mx = fmaxf(mx, s);
                    }
                    mx = fmaxf(mx, __shfl_xor(mx, 1));
                    mx = fmaxf(mx, __shfl_xor(mx, 2));
                    mx = fmaxf(mx, __shfl_xor(mx, 4));
                    mx = fmaxf(mx, __shfl_xor(mx, 8));
                    float mo = m_run[mt][r];
                    float mn = fmaxf(mo, mx);
                    float alpha = __expf(mo - mn);
                    m_run[mt][r] = mn;
                    float sm = 0.f;
#pragma unroll
                    for (int nt = 0; nt < 4; ++nt) {
                        float e = __expf(S[mt][nt][r] - mn);
                        S[mt][nt][r] = e;
                        sm += e;
                    }
                    sm += __shfl_xor(sm, 1);
                    sm += __shfl_xor(sm, 2);
                    sm += __shfl_xor(sm, 4);
                    sm += __shfl_xor(sm, 8);
                    l_run[mt][r] = l_run[mt][r] * alpha + sm;
#pragma unroll
                    for (int nt = 0; nt < 4; ++nt) ctx[mt][nt][r] *= alpha;
                }
            }
        }

        __syncthreads();  // all waves done reading K region

        // ---- stage V^T chunk (vt[d][key], hi/lo bf16, stride 72) ----
        // thread block-transposes a 4(keys) x 4(d) tile; uint2 writes along keys.
        {
            const float* vs = (c < 2) ? (vptr + c * 64 * 64) : (gvp + (c - 2) * 64 * 64);
            const int key0 = 4 * (tid & 15);
            const int d0 = 4 * ((tid >> 4) & 3) + 16 * (tid >> 6);
            f32x4 vv[4];
#pragma unroll
            for (int j = 0; j < 4; ++j)
                vv[j] = *(const f32x4*)(vs + (key0 + j) * 64 + d0);
#pragma unroll
            for (int i = 0; i < 4; ++i) {
                unsigned int h0, l0, h1, l1;
                split2(vv[0][i], vv[1][i], h0, l0);
                split2(vv[2][i], vv[3][i], h1, l1);
                int base = (d0 + i) * 72 + key0;
                *reinterpret_cast<uint2*>(kv_hi + base) = make_uint2(h0, h1);
                *reinterpret_cast<uint2*>(kv_lo + base) = make_uint2(l0, l1);
            }
        }
        __syncthreads();

        // ---- P transpose through per-wave LDS scratch (no barrier needed) ----
        bf16x8 ph[2][2], pl[2][2];
#pragma unroll
        for (int mt = 0; mt < 2; ++mt) {
#pragma unroll
            for (int nt = 0; nt < 4; ++nt)
#pragma unroll
                for (int r = 0; r < 4; ++r)
                    pw[(quad * 4 + r) * 68 + nt * 16 + c15] = S[mt][nt][r];
            __asm__ volatile("s_waitcnt lgkmcnt(0)" ::: "memory");
#pragma unroll
            for (int kk = 0; kk < 2; ++kk) {
                f32x4 a = *(const f32x4*)(pw + c15 * 68 + kk * 32 + quad * 8);
                f32x4 b = *(const f32x4*)(pw + c15 * 68 + kk * 32 + quad * 8 + 4);
                split8v(a, b, ph[mt][kk], pl[mt][kk]);
            }
            if (mt == 0) __asm__ volatile("s_waitcnt lgkmcnt(0)" ::: "memory");
        }

        // ---- ctx += P * V ----
#pragma unroll
        for (int kk = 0; kk < 2; ++kk) {
#pragma unroll
            for (int ntv = 0; ntv < 4; ++ntv) {
                int vrow = ntv * 16 + c15;
                bf16x8 vh = *(const bf16x8*)(kv_hi + vrow * 72 + kk * 32 + quad * 8);
                bf16x8 vl = *(const bf16x8*)(kv_lo + vrow * 72 + kk * 32 + quad * 8);
#pragma unroll
                for (int mt = 0; mt < 2; ++mt) {
                    f32x4 a = ctx[mt][ntv];
                    a = MFMA(ph[mt][kk], vh, a);
                    a = MFMA(pl[mt][kk], vh, a);
                    a = MFMA(ph[mt][kk], vl, a);
                    ctx[mt][ntv] = a;
                }
            }
        }
    }

    // ---- epilogue: normalize and store ----
    float* op = out + ((size_t)bh * Tt + blk * 128) * 64;
#pragma unroll
    for (int mt = 0; mt < 2; ++mt)
#pragma unroll
        for (int r = 0; r < 4; ++r) {
            float inv = 1.0f / l_run[mt][r];
            int row = wv * 32 + mt * 16 + quad * 4 + r;
#pragma unroll
            for (int ntv = 0; ntv < 4; ++ntv)
                op[row * 64 + ntv * 16 + c15] = ctx[mt][ntv][r] * inv;
        }
}

extern "C" void kernel_launch(void* const* d_in, const int* in_sizes, int n_in,
                              void* d_out, int out_size, void* d_ws, size_t ws_size,
                              hipStream_t stream) {
    (void)in_sizes; (void)n_in; (void)d_ws; (void)ws_size; (void)out_size;
    const float* q  = (const float*)d_in[0];
    const float* k  = (const float*)d_in[1];
    const float* v  = (const float*)d_in[2];
    const float* am = (const float*)d_in[3];
    const float* gk = (const float*)d_in[4];
    const float* gv = (const float*)d_in[5];
    const float* gm = (const float*)d_in[6];
    dim3 grid(32, 16, 4);
    block_attn_kernel<<<grid, dim3(256), 0, stream>>>(q, k, v, am, gk, gv, gm, (float*)d_out);
}

// Round 3
// 318.418 us; speedup vs baseline: 1.0656x; 1.0656x over previous
//
#include <hip/hip_runtime.h>
#include <hip/hip_bf16.h>

// Flash-style block attention, MI355X gfx950. Round 3.
// S^T = K·Q^T (C-layout of QK == A/B layout of mfma 16x16x16) so P^T feeds
// ctx^T = V^T·P^T with NO LDS transpose. fp32 accuracy via bf16 hi/lo 3-term.

typedef __attribute__((ext_vector_type(8))) short bf16x8;
typedef __attribute__((ext_vector_type(4))) short bf16x4;
typedef __attribute__((ext_vector_type(4))) float f32x4;

#define MFMA32(A, B, C) __builtin_amdgcn_mfma_f32_16x16x32_bf16((A), (B), (C), 0, 0, 0)
#define MFMA16(A, B, C) __builtin_amdgcn_mfma_f32_16x16x16bf16_1k((A), (B), (C), 0, 0, 0)

__device__ __forceinline__ unsigned int cvt_pk(float a, float b) {
    __hip_bfloat162 h = __float22bfloat162_rn(float2{a, b});
    union { __hip_bfloat162 h; unsigned int u; } c;
    c.h = h;
    return c.u;
}
__device__ __forceinline__ void split2(float a, float b, unsigned int& hi, unsigned int& lo) {
    unsigned int h = cvt_pk(a, b);
    float ra = a - __uint_as_float(h << 16);
    float rb = b - __uint_as_float(h & 0xFFFF0000u);
    hi = h;
    lo = cvt_pk(ra, rb);
}
__device__ __forceinline__ void split8v(f32x4 a, f32x4 b, bf16x8& hi, bf16x8& lo) {
    union { bf16x8 v; unsigned int w[4]; } H, L;
    split2(a[0], a[1], H.w[0], L.w[0]);
    split2(a[2], a[3], H.w[1], L.w[1]);
    split2(b[0], b[1], H.w[2], L.w[2]);
    split2(b[2], b[3], H.w[3], L.w[3]);
    hi = H.v; lo = L.v;
}
__device__ __forceinline__ void split4v(f32x4 s, bf16x4& hi, bf16x4& lo) {
    union { bf16x4 v; unsigned int w[2]; } H, L;
    split2(s[0], s[1], H.w[0], L.w[0]);
    split2(s[2], s[3], H.w[1], L.w[1]);
    hi = H.v; lo = L.v;
}

// LDS: K (64x72 hi/lo bf16) + V^T (64x76 hi/lo bf16) = 37888 B; epilogue reuses
// the region as [128][68] fp32 (34816 B). 37888*4 < 160K -> LDS allows 4 WG/CU.
#define LDS_BYTES 37888

__global__ __launch_bounds__(256, 3) void block_attn_kernel(
    const float* __restrict__ q, const float* __restrict__ k,
    const float* __restrict__ v, const float* __restrict__ amask,
    const float* __restrict__ gk, const float* __restrict__ gv,
    const float* __restrict__ gmask, float* __restrict__ out) {
    constexpr int Hh = 16, Tt = 4096, Gg = 128;

    __shared__ __align__(16) unsigned char lds[LDS_BYTES];
    unsigned short* k_hi = (unsigned short*)(lds);          // [64][72]
    unsigned short* k_lo = (unsigned short*)(lds + 9216);   // [64][72]
    unsigned short* v_hi = (unsigned short*)(lds + 18432);  // [64][76] V^T[d][key]
    unsigned short* v_lo = (unsigned short*)(lds + 28160);  // [64][76]
    float* o_scr = (float*)(lds);                           // [128][68] epilogue

    const int blk = blockIdx.x;
    const int bh  = blockIdx.z * Hh + blockIdx.y;
    const int tid  = threadIdx.x;
    const int lane = tid & 63;
    const int wv   = tid >> 6;
    const int c15  = lane & 15;
    const int quad = lane >> 4;

    const float* qptr = q + ((size_t)bh * Tt + blk * 128) * 64;
    const float* kptr = k + ((size_t)bh * Tt + blk * 128) * 64;
    const float* vptr = v + ((size_t)bh * Tt + blk * 128) * 64;
    const float* gkp  = gk + (size_t)bh * Gg * 64;
    const float* gvp  = gv + (size_t)bh * Gg * 64;
    const float* amp  = amask + (size_t)bh * Tt + blk * 128;
    const float* gmp  = gmask + (size_t)bh * Gg;

    // ---- Q as B-operand frags: n=c15 (q-row), k=d=32*half+quad*8+j ----
    bf16x8 qbh[2][2], qbl[2][2];
#pragma unroll
    for (int qn = 0; qn < 2; ++qn) {
        int row = wv * 32 + qn * 16 + c15;
#pragma unroll
        for (int h = 0; h < 2; ++h) {
            f32x4 a = *(const f32x4*)(qptr + row * 64 + h * 32 + quad * 8);
            f32x4 b = *(const f32x4*)(qptr + row * 64 + h * 32 + quad * 8 + 4);
            split8v(a, b, qbh[qn][h], qbl[qn][h]);
        }
    }

    const f32x4 zero4 = {0.f, 0.f, 0.f, 0.f};
    f32x4 ctx[4][2];  // ctx^T[d=dm*16+quad*4+r][q=qn*16+c15]
    float m_run[2], l_run[2];
#pragma unroll
    for (int dm = 0; dm < 4; ++dm)
#pragma unroll
        for (int qn = 0; qn < 2; ++qn) ctx[dm][qn] = zero4;
    m_run[0] = m_run[1] = -3.4e38f;
    l_run[0] = l_run[1] = 0.f;

#pragma unroll
    for (int c = 0; c < 4; ++c) {
        __syncthreads();  // prior chunk's LDS reads complete

        // ---- stage K chunk (64 keys x 64 d), stride 72, hi/lo ----
        {
            const float* ks = (c < 2) ? (kptr + c * 64 * 64) : (gkp + (c - 2) * 64 * 64);
            const int slot = tid & 15, r0 = tid >> 4;
#pragma unroll
            for (int i = 0; i < 4; ++i) {
                int row = r0 + i * 16;
                f32x4 val = *(const f32x4*)(ks + row * 64 + slot * 4);
                unsigned int h0, l0, h1, l1;
                split2(val[0], val[1], h0, l0);
                split2(val[2], val[3], h1, l1);
                int base = row * 72 + slot * 4;
                *reinterpret_cast<uint2*>(k_hi + base) = make_uint2(h0, h1);
                *reinterpret_cast<uint2*>(k_lo + base) = make_uint2(l0, l1);
            }
        }
        // ---- stage V^T chunk (vt[d][key]), stride 76, hi/lo ----
        {
            const float* vs = (c < 2) ? (vptr + c * 64 * 64) : (gvp + (c - 2) * 64 * 64);
            const int key0 = 4 * (tid & 15);
            const int d0 = 4 * ((tid >> 4) & 3) + 16 * (tid >> 6);
            f32x4 vv[4];
#pragma unroll
            for (int j = 0; j < 4; ++j)
                vv[j] = *(const f32x4*)(vs + (key0 + j) * 64 + d0);
#pragma unroll
            for (int i = 0; i < 4; ++i) {
                unsigned int h0, l0, h1, l1;
                split2(vv[0][i], vv[1][i], h0, l0);
                split2(vv[2][i], vv[3][i], h1, l1);
                int base = (d0 + i) * 76 + key0;
                *reinterpret_cast<uint2*>(v_hi + base) = make_uint2(h0, h1);
                *reinterpret_cast<uint2*>(v_lo + base) = make_uint2(l0, l1);
            }
        }
        __syncthreads();

        // ---- S^T = K·Q^T : D[m=key][n=q], lane col=q=c15, rows key=quad*4+r ----
        f32x4 S[4][2];
#pragma unroll
        for (int km = 0; km < 4; ++km)
#pragma unroll
            for (int qn = 0; qn < 2; ++qn) S[km][qn] = zero4;

#pragma unroll
        for (int km = 0; km < 4; ++km) {
            int krow = km * 16 + c15;
            bf16x8 kh0 = *(const bf16x8*)(k_hi + krow * 72 + quad * 8);
            bf16x8 kh1 = *(const bf16x8*)(k_hi + krow * 72 + quad * 8 + 32);
            bf16x8 kl0 = *(const bf16x8*)(k_lo + krow * 72 + quad * 8);
            bf16x8 kl1 = *(const bf16x8*)(k_lo + krow * 72 + quad * 8 + 32);
#pragma unroll
            for (int qn = 0; qn < 2; ++qn) {
                f32x4 a = S[km][qn];
                a = MFMA32(kh0, qbh[qn][0], a);
                a = MFMA32(kh1, qbh[qn][1], a);
                a = MFMA32(kh0, qbl[qn][0], a);
                a = MFMA32(kh1, qbl[qn][1], a);
                a = MFMA32(kl0, qbh[qn][0], a);
                a = MFMA32(kl1, qbh[qn][1], a);
                S[km][qn] = a;
            }
        }

        // ---- online softmax over keys (rows of S^T) ----
        {
            const float* mb = (c < 2) ? (amp + c * 64) : (gmp + (c - 2) * 64);
            float mv[4][4];
#pragma unroll
            for (int km = 0; km < 4; ++km)
#pragma unroll
                for (int r = 0; r < 4; ++r) mv[km][r] = mb[km * 16 + quad * 4 + r];

#pragma unroll
            for (int qn = 0; qn < 2; ++qn) {
                float mx = -3.4e38f;
#pragma unroll
                for (int km = 0; km < 4; ++km)
#pragma unroll
                    for (int r = 0; r < 4; ++r) {
                        float s = fmaf(S[km][qn][r], 0.125f, mv[km][r]);
                        S[km][qn][r] = s;
                        mx = fmaxf(mx, s);
                    }
                mx = fmaxf(mx, __shfl_xor(mx, 16));
                mx = fmaxf(mx, __shfl_xor(mx, 32));
                float mo = m_run[qn];
                float mn = fmaxf(mo, mx);
                float alpha = __expf(mo - mn);
                m_run[qn] = mn;
                float sm = 0.f;
#pragma unroll
                for (int km = 0; km < 4; ++km)
#pragma unroll
                    for (int r = 0; r < 4; ++r) {
                        float e = __expf(S[km][qn][r] - mn);
                        S[km][qn][r] = e;
                        sm += e;
                    }
                sm += __shfl_xor(sm, 16);
                sm += __shfl_xor(sm, 32);
                l_run[qn] = l_run[qn] * alpha + sm;
#pragma unroll
                for (int dm = 0; dm < 4; ++dm) {
                    ctx[dm][qn][0] *= alpha; ctx[dm][qn][1] *= alpha;
                    ctx[dm][qn][2] *= alpha; ctx[dm][qn][3] *= alpha;
                }
            }
        }

        // ---- P^T frags in-register: B[k=key=quad*4+r][n=q=c15] for MFMA16 ----
        bf16x4 ph[4][2], pl[4][2];
#pragma unroll
        for (int km = 0; km < 4; ++km)
#pragma unroll
            for (int qn = 0; qn < 2; ++qn) split4v(S[km][qn], ph[km][qn], pl[km][qn]);

        // ---- ctx^T += V^T · P^T (mfma 16x16x16, A[m=d][k=key]) ----
#pragma unroll
        for (int dm = 0; dm < 4; ++dm) {
            int drow = dm * 16 + c15;
#pragma unroll
            for (int km = 0; km < 4; ++km) {
                bf16x4 vh = *(const bf16x4*)(v_hi + drow * 76 + km * 16 + quad * 4);
                bf16x4 vl = *(const bf16x4*)(v_lo + drow * 76 + km * 16 + quad * 4);
#pragma unroll
                for (int qn = 0; qn < 2; ++qn) {
                    f32x4 a = ctx[dm][qn];
                    a = MFMA16(vh, ph[km][qn], a);
                    a = MFMA16(vh, pl[km][qn], a);
                    a = MFMA16(vl, ph[km][qn], a);
                    ctx[dm][qn] = a;
                }
            }
        }
    }

    // ---- epilogue: normalize, bounce ctx^T through LDS, coalesced store ----
    __syncthreads();
#pragma unroll
    for (int qn = 0; qn < 2; ++qn) {
        float inv = 1.0f / l_run[qn];
        int row = wv * 32 + qn * 16 + c15;
#pragma unroll
        for (int dm = 0; dm < 4; ++dm) {
            f32x4 o = ctx[dm][qn];
            o[0] *= inv; o[1] *= inv; o[2] *= inv; o[3] *= inv;
            *(f32x4*)(o_scr + row * 68 + dm * 16 + quad * 4) = o;
        }
    }
    __syncthreads();
    {
        float* op = out + ((size_t)bh * Tt + blk * 128) * 64;
        const int slot = tid & 15, r0 = tid >> 4;
#pragma unroll
        for (int i = 0; i < 8; ++i) {
            int row = r0 + i * 16;
            f32x4 val = *(const f32x4*)(o_scr + row * 68 + slot * 4);
            *(f32x4*)(op + row * 64 + slot * 4) = val;
        }
    }
}

extern "C" void kernel_launch(void* const* d_in, const int* in_sizes, int n_in,
                              void* d_out, int out_size, void* d_ws, size_t ws_size,
                              hipStream_t stream) {
    (void)in_sizes; (void)n_in; (void)d_ws; (void)ws_size; (void)out_size;
    const float* q  = (const float*)d_in[0];
    const float* k  = (const float*)d_in[1];
    const float* v  = (const float*)d_in[2];
    const float* am = (const float*)d_in[3];
    const float* gk = (const float*)d_in[4];
    const float* gv = (const float*)d_in[5];
    const float* gm = (const float*)d_in[6];
    dim3 grid(32, 16, 4);
    block_attn_kernel<<<grid, dim3(256), 0, stream>>>(q, k, v, am, gk, gv, gm, (float*)d_out);
}

// Round 4
// 258.109 us; speedup vs baseline: 1.3146x; 1.2337x over previous
//
#include <hip/hip_runtime.h>
#include <hip/hip_bf16.h>

// Flash-style block attention, MI355X gfx950. Round 4.
// 512-thread WGs (8 waves), 16 q-rows/wave -> per-wave reg state halved vs R3;
// fits __launch_bounds__(512,4) 128-reg cap with NO spills, 2 WGs/CU.
// S^T = K·Q^T; P^T stays in registers and feeds ctx^T = V^T·P^T via mfma16.
// fp32 accuracy via bf16 hi/lo split (3 MFMA per product term).

typedef __attribute__((ext_vector_type(8))) short bf16x8;
typedef __attribute__((ext_vector_type(4))) short bf16x4;
typedef __attribute__((ext_vector_type(4))) float f32x4;

#define MFMA32(A, B, C) __builtin_amdgcn_mfma_f32_16x16x32_bf16((A), (B), (C), 0, 0, 0)
#define MFMA16(A, B, C) __builtin_amdgcn_mfma_f32_16x16x16bf16_1k((A), (B), (C), 0, 0, 0)

__device__ __forceinline__ unsigned int cvt_pk(float a, float b) {
    __hip_bfloat162 h = __float22bfloat162_rn(float2{a, b});
    union { __hip_bfloat162 h; unsigned int u; } c;
    c.h = h;
    return c.u;
}
__device__ __forceinline__ void split2(float a, float b, unsigned int& hi, unsigned int& lo) {
    unsigned int h = cvt_pk(a, b);
    float ra = a - __uint_as_float(h << 16);
    float rb = b - __uint_as_float(h & 0xFFFF0000u);
    hi = h;
    lo = cvt_pk(ra, rb);
}
__device__ __forceinline__ void split8v(f32x4 a, f32x4 b, bf16x8& hi, bf16x8& lo) {
    union { bf16x8 v; unsigned int w[4]; } H, L;
    split2(a[0], a[1], H.w[0], L.w[0]);
    split2(a[2], a[3], H.w[1], L.w[1]);
    split2(b[0], b[1], H.w[2], L.w[2]);
    split2(b[2], b[3], H.w[3], L.w[3]);
    hi = H.v; lo = L.v;
}
__device__ __forceinline__ void split4v(f32x4 s, bf16x4& hi, bf16x4& lo) {
    union { bf16x4 v; unsigned int w[2]; } H, L;
    split2(s[0], s[1], H.w[0], L.w[0]);
    split2(s[2], s[3], H.w[1], L.w[1]);
    hi = H.v; lo = L.v;
}

// LDS: K [64][72] hi/lo + V^T [64][76] hi/lo = 37888 B; epilogue reuses region
// as [128][68] fp32 (34816 B). 37888*2 well under 160K.
#define LDS_BYTES 37888

__global__ __launch_bounds__(512, 4) void block_attn_kernel(
    const float* __restrict__ q, const float* __restrict__ k,
    const float* __restrict__ v, const float* __restrict__ amask,
    const float* __restrict__ gk, const float* __restrict__ gv,
    const float* __restrict__ gmask, float* __restrict__ out) {
    constexpr int Hh = 16, Tt = 4096, Gg = 128;

    __shared__ __align__(16) unsigned char lds[LDS_BYTES];
    unsigned short* k_hi = (unsigned short*)(lds);          // [64][72]
    unsigned short* k_lo = (unsigned short*)(lds + 9216);   // [64][72]
    unsigned short* v_hi = (unsigned short*)(lds + 18432);  // [64][76] V^T[d][key]
    unsigned short* v_lo = (unsigned short*)(lds + 28160);  // [64][76]
    float* o_scr = (float*)(lds);                           // [128][68] epilogue

    const int blk = blockIdx.x;
    const int bh  = blockIdx.z * Hh + blockIdx.y;
    const int tid  = threadIdx.x;
    const int lane = tid & 63;
    const int wv   = tid >> 6;      // 0..7, wave owns q-rows [wv*16, wv*16+16)
    const int c15  = lane & 15;
    const int quad = lane >> 4;

    const float* qptr = q + ((size_t)bh * Tt + blk * 128) * 64;
    const float* kptr = k + ((size_t)bh * Tt + blk * 128) * 64;
    const float* vptr = v + ((size_t)bh * Tt + blk * 128) * 64;
    const float* gkp  = gk + (size_t)bh * Gg * 64;
    const float* gvp  = gv + (size_t)bh * Gg * 64;
    const float* amp  = amask + (size_t)bh * Tt + blk * 128;
    const float* gmp  = gmask + (size_t)bh * Gg;

    // ---- Q as B-operand frags: n=c15 (q-row), k=d=32*half+quad*8+j ----
    bf16x8 qbh[2], qbl[2];
    {
        int row = wv * 16 + c15;
#pragma unroll
        for (int h = 0; h < 2; ++h) {
            f32x4 a = *(const f32x4*)(qptr + row * 64 + h * 32 + quad * 8);
            f32x4 b = *(const f32x4*)(qptr + row * 64 + h * 32 + quad * 8 + 4);
            split8v(a, b, qbh[h], qbl[h]);
        }
    }

    const f32x4 zero4 = {0.f, 0.f, 0.f, 0.f};
    f32x4 ctx[4];  // ctx^T[d=dm*16+quad*4+r][q=c15]
#pragma unroll
    for (int dm = 0; dm < 4; ++dm) ctx[dm] = zero4;
    float m_run = -3.4e38f, l_run = 0.f;

#pragma unroll
    for (int c = 0; c < 4; ++c) {
        __syncthreads();  // prior chunk's LDS reads complete

        if (wv < 4) {
            // ---- waves 0-3: stage K chunk (64 keys x 64 d), stride 72 ----
            const float* ks = (c < 2) ? (kptr + c * 64 * 64) : (gkp + (c - 2) * 64 * 64);
            const int slot = tid & 15, r0 = (tid >> 4) & 15;
#pragma unroll
            for (int i = 0; i < 4; ++i) {
                int row = r0 + i * 16;
                f32x4 val = *(const f32x4*)(ks + row * 64 + slot * 4);
                unsigned int h0, l0, h1, l1;
                split2(val[0], val[1], h0, l0);
                split2(val[2], val[3], h1, l1);
                int base = row * 72 + slot * 4;
                *reinterpret_cast<uint2*>(k_hi + base) = make_uint2(h0, h1);
                *reinterpret_cast<uint2*>(k_lo + base) = make_uint2(l0, l1);
            }
        } else {
            // ---- waves 4-7: stage V^T chunk (vt[d][key]), stride 76 ----
            const float* vs = (c < 2) ? (vptr + c * 64 * 64) : (gvp + (c - 2) * 64 * 64);
            const int t = tid - 256;
            const int key0 = 4 * (t & 15);
            const int d0 = 4 * ((t >> 4) & 3) + 16 * (t >> 6);
            f32x4 vv[4];
#pragma unroll
            for (int j = 0; j < 4; ++j)
                vv[j] = *(const f32x4*)(vs + (key0 + j) * 64 + d0);
#pragma unroll
            for (int i = 0; i < 4; ++i) {
                unsigned int h0, l0, h1, l1;
                split2(vv[0][i], vv[1][i], h0, l0);
                split2(vv[2][i], vv[3][i], h1, l1);
                int base = (d0 + i) * 76 + key0;
                *reinterpret_cast<uint2*>(v_hi + base) = make_uint2(h0, h1);
                *reinterpret_cast<uint2*>(v_lo + base) = make_uint2(l0, l1);
            }
        }
        __syncthreads();

        // ---- S^T = K·Q^T : D[m=key=km*16+quad*4+r][n=q=c15] ----
        f32x4 S[4];
#pragma unroll
        for (int km = 0; km < 4; ++km) S[km] = zero4;

#pragma unroll
        for (int km = 0; km < 4; ++km) {
            int krow = km * 16 + c15;
            bf16x8 kh0 = *(const bf16x8*)(k_hi + krow * 72 + quad * 8);
            bf16x8 kh1 = *(const bf16x8*)(k_hi + krow * 72 + quad * 8 + 32);
            bf16x8 kl0 = *(const bf16x8*)(k_lo + krow * 72 + quad * 8);
            bf16x8 kl1 = *(const bf16x8*)(k_lo + krow * 72 + quad * 8 + 32);
            f32x4 a = S[km];
            a = MFMA32(kh0, qbh[0], a);
            a = MFMA32(kh1, qbh[1], a);
            a = MFMA32(kh0, qbl[0], a);
            a = MFMA32(kh1, qbl[1], a);
            a = MFMA32(kl0, qbh[0], a);
            a = MFMA32(kl1, qbh[1], a);
            S[km] = a;
        }

        // ---- online softmax over keys (rows of S^T) + P^T frags ----
        bf16x4 ph[4], pl[4];
        {
            const float* mb = (c < 2) ? (amp + c * 64) : (gmp + (c - 2) * 64);
            float mx = -3.4e38f;
#pragma unroll
            for (int km = 0; km < 4; ++km)
#pragma unroll
                for (int r = 0; r < 4; ++r) {
                    float s = fmaf(S[km][r], 0.125f, mb[km * 16 + quad * 4 + r]);
                    S[km][r] = s;
                    mx = fmaxf(mx, s);
                }
            mx = fmaxf(mx, __shfl_xor(mx, 16));
            mx = fmaxf(mx, __shfl_xor(mx, 32));
            float mo = m_run;
            float mn = fmaxf(mo, mx);
            float alpha = __expf(mo - mn);
            m_run = mn;
            float sm = 0.f;
#pragma unroll
            for (int km = 0; km < 4; ++km)
#pragma unroll
                for (int r = 0; r < 4; ++r) {
                    float e = __expf(S[km][r] - mn);
                    S[km][r] = e;
                    sm += e;
                }
            sm += __shfl_xor(sm, 16);
            sm += __shfl_xor(sm, 32);
            l_run = l_run * alpha + sm;
#pragma unroll
            for (int km = 0; km < 4; ++km) split4v(S[km], ph[km], pl[km]);
#pragma unroll
            for (int dm = 0; dm < 4; ++dm) {
                ctx[dm][0] *= alpha; ctx[dm][1] *= alpha;
                ctx[dm][2] *= alpha; ctx[dm][3] *= alpha;
            }
        }

        // ---- ctx^T += V^T · P^T (mfma 16x16x16, A[m=d][k=key=quad*4+r]) ----
#pragma unroll
        for (int dm = 0; dm < 4; ++dm) {
            int drow = dm * 16 + c15;
            f32x4 a = ctx[dm];
#pragma unroll
            for (int km = 0; km < 4; ++km) {
                bf16x4 vh = *(const bf16x4*)(v_hi + drow * 76 + km * 16 + quad * 4);
                bf16x4 vl = *(const bf16x4*)(v_lo + drow * 76 + km * 16 + quad * 4);
                a = MFMA16(vh, ph[km], a);
                a = MFMA16(vh, pl[km], a);
                a = MFMA16(vl, ph[km], a);
            }
            ctx[dm] = a;
        }
    }

    // ---- epilogue: normalize, bounce ctx^T through LDS, coalesced store ----
    __syncthreads();
    {
        float inv = 1.0f / l_run;
        int row = wv * 16 + c15;
#pragma unroll
        for (int dm = 0; dm < 4; ++dm) {
            f32x4 o = ctx[dm];
            o[0] *= inv; o[1] *= inv; o[2] *= inv; o[3] *= inv;
            *(f32x4*)(o_scr + row * 68 + dm * 16 + quad * 4) = o;
        }
    }
    __syncthreads();
    {
        float* op = out + ((size_t)bh * Tt + blk * 128) * 64;
        const int slot = tid & 15, r0 = tid >> 4;  // r0 0..31
#pragma unroll
        for (int i = 0; i < 4; ++i) {
            int row = r0 + i * 32;
            f32x4 val = *(const f32x4*)(o_scr + row * 68 + slot * 4);
            *(f32x4*)(op + row * 64 + slot * 4) = val;
        }
    }
}

extern "C" void kernel_launch(void* const* d_in, const int* in_sizes, int n_in,
                              void* d_out, int out_size, void* d_ws, size_t ws_size,
                              hipStream_t stream) {
    (void)in_sizes; (void)n_in; (void)d_ws; (void)ws_size; (void)out_size;
    const float* q  = (const float*)d_in[0];
    const float* k  = (const float*)d_in[1];
    const float* v  = (const float*)d_in[2];
    const float* am = (const float*)d_in[3];
    const float* gk = (const float*)d_in[4];
    const float* gv = (const float*)d_in[5];
    const float* gm = (const float*)d_in[6];
    dim3 grid(32, 16, 4);
    block_attn_kernel<<<grid, dim3(512), 0, stream>>>(q, k, v, am, gk, gv, gm, (float*)d_out);
}